// Round 5
// baseline (130.885 us; speedup 1.0000x reference)
//
#include <hip/hip_runtime.h>

typedef short bf16x8 __attribute__((ext_vector_type(8)));
typedef float f32x4  __attribute__((ext_vector_type(4)));

#define WAVES 16
#define BLOCK 1024
#define SPAD  448             // S padded to 7*64
#define KDIM  (4 * SPAD)      // 1792 real-K for f1 (k = 4s + 2c + i)
#define K2    192             // f2 real-K (4*41=164 padded to 192)
#define ROWS  80              // real-expanded output rows (o,p,reim)
#define NCH   7               // 7 chunks x 64 s
#define FSTR  528             // Fch column stride bytes: 132 dw == 4 mod 32 -> bank-even

#define ESH_OFF 0                  // ushort4 [41][64] = 20992
#define FCH_OFF 20992              // 64 cols * 528 B  = 33792
#define BM_OFF  54784              // ushort [80][64]  = 10240
#define LDS_BYTES 65024
#define PACC_OFF FCH_OFF           // alias after chunks: float4[16][64] = 16384
#define ASH_OFF  (FCH_OFF + 16384) // alias: ushort[80][64] = 10240

__device__ __forceinline__ unsigned short f2bf(float f) {
    union { float f; unsigned u; } v; v.f = f;
    unsigned r = v.u + 0x7FFFu + ((v.u >> 16) & 1u);   // RNE
    return (unsigned short)(r >> 16);
}
__device__ __forceinline__ float bf2f(unsigned short h) {
    union { unsigned u; float f; } v; v.u = ((unsigned)h) << 16;
    return v.f;
}

// One prep kernel: W1' [80][1792], W2' [80][192] (pol-flip baked in), meta [S] int4.
__global__ void prep_all_kernel(const float* __restrict__ W1,
                                const float* __restrict__ W2,
                                const float* __restrict__ pbcC,
                                const int* __restrict__ m_idx,
                                const int* __restrict__ n_idx,
                                unsigned short* __restrict__ Wp,
                                unsigned short* __restrict__ W2p,
                                int4* __restrict__ meta, int S) {
    int idx = blockIdx.x * 256 + threadIdx.x;
    if (idx < ROWS * KDIM) {
        int row = idx / KDIM, k = idx - row * KDIM;
        int o = row >> 2, p = (row >> 1) & 1, r = row & 1;
        int s = k >> 2,  c = (k >> 1) & 1,  i = k & 1;
        float v = 0.f;
        if (s < S) {
            int j = i ^ p;
            float wr = W1[((size_t)(o * 2 + j) * S + s) * 2 + 0];
            float wi = W1[((size_t)(o * 2 + j) * S + s) * 2 + 1];
            v = (c == 0) ? (r == 0 ? wr : wi) : (r == 0 ? -wi : wr);
        }
        Wp[idx] = f2bf(v);
        return;
    }
    idx -= ROWS * KDIM;
    if (idx < ROWS * K2) {
        int row = idx / K2, k = idx - row * K2;
        int o = row >> 2, p = (row >> 1) & 1, r = row & 1;
        int m = k >> 2,  c = (k >> 1) & 1,  i = k & 1;
        float v = 0.f;
        if (m < 41) {
            int j = i ^ p;
            float wr = W2[((o * 2 + j) * 41 + m) * 2 + 0];
            float wi = W2[((o * 2 + j) * 41 + m) * 2 + 1];
            v = (c == 0) ? (r == 0 ? wr : wi) : (r == 0 ? -wi : wr);
        }
        W2p[idx] = f2bf(v);
        return;
    }
    idx -= ROWS * K2;
    if (idx < S) {
        meta[idx] = make_int4(m_idx[idx], n_idx[idx],
                              __float_as_int(pbcC[idx * 2 + 0]),
                              __float_as_int(pbcC[idx * 2 + 1]));
    }
}

__global__ __launch_bounds__(BLOCK) void eqsonn_kernel(
    const float* __restrict__ x,            // [B,41,2,2]
    const float* __restrict__ task,         // [B,4]
    const unsigned short* __restrict__ Wp,  // [80][KDIM]
    const unsigned short* __restrict__ W2p, // [80][K2]
    const int4* __restrict__ meta,          // [S] {m,n,Cr,Ci}
    const float* __restrict__ b1,           // [10,2]
    const float* __restrict__ b2,           // [10,2]
    float* __restrict__ out,                // [B,2,2]
    int B, int S)
{
    __shared__ alignas(16) char ldsb[LDS_BYTES];
    ushort4* Esh = (ushort4*)(ldsb + ESH_OFF);   // [k*64 + col]

    const int tid  = threadIdx.x;
    const int lane = tid & 63;
    const int wave = tid >> 6;
    const int b0   = blockIdx.x * 64;
    const int b    = b0 + lane;
    const int quad = lane >> 4;
    const int l15  = lane & 15;
    const int wu   = __builtin_amdgcn_readfirstlane(wave);

    // job assignment: 12 jobs of 32(16) rows x 16 cols
    const bool has  = (wave < 12);
    const int  mtp  = wu >> 2;             // 0,1,2
    const int  nt   = wu & 3;              // 0..3
    const bool dual = (mtp < 2);
    const int  mt0  = dual ? mtp * 2 : 4;

    // ---- stage E (bf16) [k][col] ----
    for (int e = tid; e < 41 * 64; e += BLOCK) {
        int bb = e / 41, k = e - bb * 41;
        int bs = b0 + bb; if (bs > B - 1) bs = B - 1;
        float4 v = ((const float4*)x)[(size_t)bs * 41 + k];
        ushort4 h;
        h.x = f2bf(v.x); h.y = f2bf(v.y); h.z = f2bf(v.z); h.w = f2bf(v.w);
        Esh[k * 64 + bb] = h;
    }
    __syncthreads();

    // ==== f2 via MFMA ====
    // produce Ef into Fch: 48 slots of 4 k', wave w fills sl = 3w+j
#pragma unroll
    for (int j = 0; j < 3; ++j) {
        int sl = wu * 3 + j;
        ushort4 h; h.x = 0; h.y = 0; h.z = 0; h.w = 0;
        if (sl < 41) {
            ushort4 e = Esh[sl * 64 + lane];
            h.x = e.x; h.y = e.z; h.z = e.y; h.w = e.w;  // [ReP0,ReP1,ImP0,ImP1]
        }
        *(ushort4*)(ldsb + FCH_OFF + lane * FSTR + sl * 8) = h;
    }
    __syncthreads();

    f32x4 facc0 = {0.f,0.f,0.f,0.f}, facc1 = {0.f,0.f,0.f,0.f};
    if (has) {
        unsigned bbase = FCH_OFF + (unsigned)(nt * 16 + l15) * FSTR + quad * 16;
        const unsigned short* a0r = W2p + (size_t)(mt0 * 16 + l15) * K2 + quad * 8;
#pragma unroll
        for (int kk = 0; kk < 6; ++kk) {
            bf16x8 bfr = *(const bf16x8*)(ldsb + bbase + kk * 64);
            bf16x8 a0  = *(const bf16x8*)(a0r + kk * 32);
            facc0 = __builtin_amdgcn_mfma_f32_16x16x32_bf16(a0, bfr, facc0, 0, 0, 0);
            if (dual) {
                bf16x8 a1 = *(const bf16x8*)(a0r + 16 * K2 + kk * 32);
                facc1 = __builtin_amdgcn_mfma_f32_16x16x32_bf16(a1, bfr, facc1, 0, 0, 0);
            }
        }
        unsigned short* BmSh = (unsigned short*)(ldsb + BM_OFF);
        int col = nt * 16 + l15;
#pragma unroll
        for (int reg = 0; reg < 4; ++reg) {
            int row = mt0 * 16 + quad * 4 + reg;   // C/D: row=quad*4+reg, col=l15
            BmSh[row * 64 + col] = f2bf(facc0[reg]);
            if (dual) BmSh[(row + 16) * 64 + col] = f2bf(facc1[reg]);
        }
    }
    __syncthreads();   // Fch consumed -> reusable for f1 chunks

    // ==== f1 chunks: produce F (all waves) / consume MFMA (12 jobs) ====
    f32x4 acc0 = {0.f,0.f,0.f,0.f}, acc1 = {0.f,0.f,0.f,0.f};
    float pbc0 = 0.f, pbc1 = 0.f, pbc2 = 0.f, pbc3 = 0.f;

    for (int ch = 0; ch < NCH; ++ch) {
        unsigned pk[8];
#pragma unroll
        for (int j = 0; j < 4; ++j) {
            int s = ch * 64 + wu * 4 + j;     // wave-uniform
            unsigned short h0 = 0, h1 = 0, h2 = 0, h3 = 0;
            if (s < S) {
                int4 mt4 = meta[s];           // s_load_dwordx4
                int m = mt4.x, n = mt4.y;
                float Cr = __int_as_float(mt4.z), Ci = __int_as_float(mt4.w);
                ushort4 EmH = Esh[(20 + m) * 64 + lane];
                ushort4 EbH = Esh[(20 + m + n) * 64 + lane];
                ushort4 EnH = Esh[(20 + n) * 64 + lane];
                float Emx = bf2f(EmH.x), Emy = bf2f(EmH.y), Emz = bf2f(EmH.z), Emw = bf2f(EmH.w);
                float Ebx = bf2f(EbH.x), Eby = bf2f(EbH.y), Ebz = bf2f(EbH.z), Ebw = bf2f(EbH.w);
                float Enx = bf2f(EnH.x), Eny = bf2f(EnH.y), Enz = bf2f(EnH.z), Enw = bf2f(EnH.w);
                float sr = Emx * Ebx + Emy * Eby + Emz * Ebz + Emw * Ebw;
                float si = Emy * Ebx - Emx * Eby + Emw * Ebz - Emz * Ebw;
                float F0r = sr * Enx - si * Eny, F0i = sr * Eny + si * Enx;
                float F1r = sr * Enz - si * Enw, F1i = sr * Enw + si * Enz;
                pbc0 += F0r * Cr - F0i * Ci; pbc1 += F0r * Ci + F0i * Cr;
                pbc2 += F1r * Cr - F1i * Ci; pbc3 += F1r * Ci + F1i * Cr;
                h0 = f2bf(F0r); h1 = f2bf(F1r); h2 = f2bf(F0i); h3 = f2bf(F1i);
            }
            pk[j * 2 + 0] = (unsigned)h0 | ((unsigned)h1 << 16);
            pk[j * 2 + 1] = (unsigned)h2 | ((unsigned)h3 << 16);
        }
        // 2x b128 write at col*528 + wave*32 : bank-even, conflict-free
        char* wp = ldsb + FCH_OFF + lane * FSTR + wu * 32;
        *(uint4*)(wp)      = make_uint4(pk[0], pk[1], pk[2], pk[3]);
        *(uint4*)(wp + 16) = make_uint4(pk[4], pk[5], pk[6], pk[7]);
        __syncthreads();

        if (has) {
            unsigned bbase = FCH_OFF + (unsigned)(nt * 16 + l15) * FSTR + quad * 16;
            const unsigned short* a0r =
                Wp + (size_t)(mt0 * 16 + l15) * KDIM + ch * 256 + quad * 8;
#pragma unroll
            for (int kk = 0; kk < 8; ++kk) {
                bf16x8 bfr = *(const bf16x8*)(ldsb + bbase + kk * 64);
                bf16x8 a0  = *(const bf16x8*)(a0r + kk * 32);
                acc0 = __builtin_amdgcn_mfma_f32_16x16x32_bf16(a0, bfr, acc0, 0, 0, 0);
                if (dual) {
                    bf16x8 a1 = *(const bf16x8*)(a0r + (size_t)16 * KDIM + kk * 32);
                    acc1 = __builtin_amdgcn_mfma_f32_16x16x32_bf16(a1, bfr, acc1, 0, 0, 0);
                }
            }
        }
        __syncthreads();
    }

    // ---- stage partials into aliases over Fch ----
    float4* pAcc = (float4*)(ldsb + PACC_OFF);
    pAcc[wave * 64 + lane] = make_float4(pbc0, pbc1, pbc2, pbc3);
    if (has) {
        unsigned short* Ash = (unsigned short*)(ldsb + ASH_OFF);
        int col = nt * 16 + l15;
#pragma unroll
        for (int reg = 0; reg < 4; ++reg) {
            int row = mt0 * 16 + quad * 4 + reg;
            Ash[row * 64 + col] = f2bf(acc0[reg]);
            if (dual) Ash[(row + 16) * 64 + col] = f2bf(acc1[reg]);
        }
    }
    __syncthreads();

    // ---- epilogue: wave 0, lane = batch ----
    if (wave == 0) {
        float p0 = 0.f, p1 = 0.f, p2 = 0.f, p3 = 0.f;
#pragma unroll
        for (int w = 0; w < WAVES; ++w) {
            float4 a = pAcc[w * 64 + lane];
            p0 += a.x; p1 += a.y; p2 += a.z; p3 += a.w;
        }
        unsigned short* BmSh = (unsigned short*)(ldsb + BM_OFF);
        unsigned short* Ash  = (unsigned short*)(ldsb + ASH_OFF);
        float t0 = 0.f, t1 = 0.f, t2 = 0.f, t3 = 0.f;
#pragma unroll
        for (int o = 0; o < 10; ++o) {
            float b2r = b2[o * 2 + 0], b2i = b2[o * 2 + 1];
            float b1r = b1[o * 2 + 0], b1i = b1[o * 2 + 1];
            int rb = o * 4;
            float B0r = bf2f(BmSh[(rb + 0) * 64 + lane]) + b2r;
            float B0i = bf2f(BmSh[(rb + 1) * 64 + lane]) + b2i;
            float B1r = bf2f(BmSh[(rb + 2) * 64 + lane]) + b2r;
            float B1i = bf2f(BmSh[(rb + 3) * 64 + lane]) + b2i;
            float A0r = bf2f(Ash[(rb + 0) * 64 + lane]) + b1r;
            float A0i = bf2f(Ash[(rb + 1) * 64 + lane]) + b1i;
            float A1r = bf2f(Ash[(rb + 2) * 64 + lane]) + b1r;
            float A1i = bf2f(Ash[(rb + 3) * 64 + lane]) + b1i;
            // A*B*conj(B) + conj(A)*B*B = 2*Re(A*conj(B)) * B
            float g0 = 2.f * (A0r * B0r + A0i * B0i);
            t0 += g0 * B0r; t1 += g0 * B0i;
            float g1 = 2.f * (A1r * B1r + A1i * B1i);
            t2 += g1 * B1r; t3 += g1 * B1i;
        }
        if (b < B) {
            float dbm = task[(size_t)b * 4 + 0];
            float P   = exp2f(dbm * 0.33219280948873623f) * 0.5f; // 10^(dbm/10)/2
            float kP2 = 3.1622776601683794e-05f * P * P;          // 1e-4/sqrt(10)*P^2
            float4 Ec = ((const float4*)x)[(size_t)b * 41 + 20];  // fp32 center symbol
            float4 o4;
            o4.x = Ec.x + P * p0 + kP2 * t0;
            o4.y = Ec.y + P * p1 + kP2 * t1;
            o4.z = Ec.z + P * p2 + kP2 * t2;
            o4.w = Ec.w + P * p3 + kP2 * t3;
            ((float4*)out)[b] = o4;
        }
    }
}

extern "C" void kernel_launch(void* const* d_in, const int* in_sizes, int n_in,
                              void* d_out, int out_size, void* d_ws, size_t ws_size,
                              hipStream_t stream) {
    const float* x     = (const float*)d_in[0];
    const float* task  = (const float*)d_in[1];
    const float* pbcC  = (const float*)d_in[2];
    const float* W1    = (const float*)d_in[3];
    const float* b1    = (const float*)d_in[4];
    const float* W2    = (const float*)d_in[5];
    const float* b2    = (const float*)d_in[6];
    const int*   m_idx = (const int*)d_in[7];
    const int*   n_idx = (const int*)d_in[8];
    float* out = (float*)d_out;

    int S = in_sizes[7];
    int B = in_sizes[0] / (41 * 2 * 2);

    unsigned short* Wp  = (unsigned short*)d_ws;                      // 286720 B
    unsigned short* W2p = (unsigned short*)((char*)d_ws + 286720);    // 30720 B
    int4*           met = (int4*)((char*)d_ws + 317440);              // S*16 B

    int prep_elems = ROWS * KDIM + ROWS * K2 + S;
    prep_all_kernel<<<(prep_elems + 255) / 256, 256, 0, stream>>>(
        W1, W2, pbcC, m_idx, n_idx, Wp, W2p, met, S);

    int grid = (B + 63) / 64;
    eqsonn_kernel<<<grid, BLOCK, 0, stream>>>(x, task, Wp, W2p, met, b1, b2,
                                              out, B, S);
}

// Round 6
// 116.833 us; speedup vs baseline: 1.1203x; 1.1203x over previous
//
#include <hip/hip_runtime.h>
#include <hip/hip_bf16.h>

typedef short bf16x8 __attribute__((ext_vector_type(8)));
typedef float f32x4  __attribute__((ext_vector_type(4)));

#define WAVES 8
#define BLOCK 512
#define NCOL  32              // batch columns per block
#define SPAD  448             // S padded to 7*64
#define KDIM  (4 * SPAD)      // 1792 real-K for f1 (k = 4s + 2c + i)
#define K2    192             // f2 real-K (4*48, 41 used)
#define ROWS  80              // real-expanded rows (o,p,reim)
#define NCH   7               // 7 chunks x 64 s
#define FSTR  528             // F column stride bytes (132 dw == 4 mod 32)

#define ESH_OFF 0                      // float4 [41][32] = 20992
#define FB0_OFF 20992                  // 32 cols * 528   = 16896
#define FB1_OFF (FB0_OFF + 16896)      //                 = 16896
#define BM_OFF  (FB1_OFF + 16896)      // ushort [80][32] = 5120
#define LDS_BYTES (BM_OFF + 5120)      // 59904 -> 2 blocks/CU
#define PACC_OFF FB0_OFF               // alias: float4[8][64] = 8192
#define ASH_OFF  (FB0_OFF + 8192)      // alias: ushort[80][32] = 5120

__device__ __forceinline__ unsigned short f2bf(float f) {
    union { float f; unsigned u; } v; v.f = f;
    unsigned r = v.u + 0x7FFFu + ((v.u >> 16) & 1u);
    return (unsigned short)(r >> 16);
}
__device__ __forceinline__ float bf2f(unsigned short h) {
    union { unsigned u; float f; } v; v.u = ((unsigned)h) << 16;
    return v.f;
}
__device__ __forceinline__ unsigned pk2(float a, float b) {
    __hip_bfloat162 h = __float22bfloat162_rn(make_float2(a, b));
    unsigned u; __builtin_memcpy(&u, &h, 4); return u;
}

// prep: W1' [80][1792], W2' [80][192] (pol-flip baked in), meta [S] int4
__global__ void prep_all_kernel(const float* __restrict__ W1,
                                const float* __restrict__ W2,
                                const float* __restrict__ pbcC,
                                const int* __restrict__ m_idx,
                                const int* __restrict__ n_idx,
                                unsigned short* __restrict__ Wp,
                                unsigned short* __restrict__ W2p,
                                int4* __restrict__ meta, int S) {
    int idx = blockIdx.x * 256 + threadIdx.x;
    if (idx < ROWS * KDIM) {
        int row = idx / KDIM, k = idx - row * KDIM;
        int o = row >> 2, p = (row >> 1) & 1, r = row & 1;
        int s = k >> 2,  c = (k >> 1) & 1,  i = k & 1;
        float v = 0.f;
        if (s < S) {
            int j = i ^ p;
            float wr = W1[((size_t)(o * 2 + j) * S + s) * 2 + 0];
            float wi = W1[((size_t)(o * 2 + j) * S + s) * 2 + 1];
            v = (c == 0) ? (r == 0 ? wr : wi) : (r == 0 ? -wi : wr);
        }
        Wp[idx] = f2bf(v);
        return;
    }
    idx -= ROWS * KDIM;
    if (idx < ROWS * K2) {
        int row = idx / K2, k = idx - row * K2;
        int o = row >> 2, p = (row >> 1) & 1, r = row & 1;
        int m = k >> 2,  c = (k >> 1) & 1,  i = k & 1;
        float v = 0.f;
        if (m < 41) {
            int j = i ^ p;
            float wr = W2[((o * 2 + j) * 41 + m) * 2 + 0];
            float wi = W2[((o * 2 + j) * 41 + m) * 2 + 1];
            v = (c == 0) ? (r == 0 ? wr : wi) : (r == 0 ? -wi : wr);
        }
        W2p[idx] = f2bf(v);
        return;
    }
    idx -= ROWS * K2;
    if (idx < S) {
        meta[idx] = make_int4(m_idx[idx], n_idx[idx],
                              __float_as_int(pbcC[idx * 2 + 0]),
                              __float_as_int(pbcC[idx * 2 + 1]));
    }
}

__global__ __launch_bounds__(BLOCK, 4) void eqsonn_kernel(
    const float* __restrict__ x,            // [B,41,2,2]
    const float* __restrict__ task,         // [B,4]
    const unsigned short* __restrict__ Wp,  // [80][KDIM]
    const unsigned short* __restrict__ W2p, // [80][K2]
    const int4* __restrict__ meta,          // [S] {m,n,Cr,Ci}
    const float* __restrict__ b1,           // [10,2]
    const float* __restrict__ b2,           // [10,2]
    float* __restrict__ out,                // [B,2,2]
    int B, int S)
{
    __shared__ alignas(16) char ldsb[LDS_BYTES];
    float4* Esh = (float4*)(ldsb + ESH_OFF);   // [k*32 + col], fp32

    const int tid  = threadIdx.x;
    const int lane = tid & 63;
    const int wave = tid >> 6;
    const int col  = lane & 31;
    const int g    = lane >> 5;
    const int quad = lane >> 4;
    const int l15  = lane & 15;
    const int b0   = blockIdx.x * NCOL;
    const int b    = b0 + col;
    const int wu   = __builtin_amdgcn_readfirstlane(wave);

    // consumer jobs: waves 0-3 dual-M (mt {0,1}/{2,3} x nt), 4-5 single mt4, 6-7 none
    const bool dual = (wu < 4);
    const bool has  = (wu < 6);
    const int  mt0  = dual ? (wu >> 1) * 2 : 4;
    const int  nt   = wu & 1;

    // ---- stage E fp32 [k][col] ----
    for (int e = tid; e < 41 * NCOL; e += BLOCK) {
        int bb = e / 41, k = e - bb * 41;
        int bs = b0 + bb; if (bs > B - 1) bs = B - 1;
        Esh[k * NCOL + bb] = ((const float4*)x)[(size_t)bs * 41 + k];
    }
    __syncthreads();

    // ---- f2 produce Ef into FB0: slot sl covers k-block [ReP0,ReP1,ImP0,ImP1]
#pragma unroll
    for (int j = 0; j < 3; ++j) {
        int sl = wu * 6 + 2 * j + g;
        uint2 h = make_uint2(0u, 0u);
        if (sl < 41) {
            float4 e = Esh[sl * NCOL + col];
            h.x = pk2(e.x, e.z); h.y = pk2(e.y, e.w);
        }
        *(uint2*)(ldsb + FB0_OFF + col * FSTR + sl * 8) = h;
    }
    __syncthreads();

    float pbc0 = 0.f, pbc1 = 0.f, pbc2 = 0.f, pbc3 = 0.f;
    f32x4 acc0 = {0.f,0.f,0.f,0.f}, acc1 = {0.f,0.f,0.f,0.f};

    // producer lambda-ish macro body as a function scope helper
    auto produce = [&](int chunkbase, int bufoff) {
#pragma unroll
        for (int j = 0; j < 4; ++j) {
            int s0 = chunkbase + wu * 8 + 2 * j;        // wave-uniform
            int c0 = s0 < S - 1 ? s0 : S - 1;
            int c1 = s0 + 1 < S - 1 ? s0 + 1 : S - 1;
            int4 ma = meta[c0];                          // s_load_dwordx4
            int4 mb = meta[c1];
            int  m  = g ? mb.x : ma.x;
            int  n  = g ? mb.y : ma.y;
            float Cr = __int_as_float(g ? mb.z : ma.z);
            float Ci = __int_as_float(g ? mb.w : ma.w);
            int s = s0 + g;
            float4 Em = Esh[(20 + m) * NCOL + col];
            float4 Eb = Esh[(20 + m + n) * NCOL + col];
            float4 En = Esh[(20 + n) * NCOL + col];
            float sr = Em.x * Eb.x + Em.y * Eb.y + Em.z * Eb.z + Em.w * Eb.w;
            float si = Em.y * Eb.x - Em.x * Eb.y + Em.w * Eb.z - Em.z * Eb.w;
            float F0r = sr * En.x - si * En.y, F0i = sr * En.y + si * En.x;
            float F1r = sr * En.z - si * En.w, F1i = sr * En.w + si * En.z;
            uint2 h = make_uint2(0u, 0u);
            if (s < S) {
                pbc0 += F0r * Cr - F0i * Ci; pbc1 += F0r * Ci + F0i * Cr;
                pbc2 += F1r * Cr - F1i * Ci; pbc3 += F1r * Ci + F1i * Cr;
                h.x = pk2(F0r, F1r); h.y = pk2(F0i, F1i);
            }
            *(uint2*)(ldsb + bufoff + col * FSTR + (wu * 8 + 2 * j + g) * 8) = h;
        }
    };

    // ---- interval -1: produce ch0 into FB1; f2 consume from FB0 -> BM ----
    {
        f32x4 fa0 = {0.f,0.f,0.f,0.f}, fa1 = {0.f,0.f,0.f,0.f};
        bf16x8 A2f[6], A2g[6];
        if (has) {
            const unsigned short* ap = W2p + (size_t)(mt0 * 16 + l15) * K2 + quad * 8;
#pragma unroll
            for (int kk = 0; kk < 6; ++kk) {
                A2f[kk] = *(const bf16x8*)(ap + kk * 32);
                if (dual) A2g[kk] = *(const bf16x8*)(ap + 16 * K2 + kk * 32);
            }
        }
        produce(0, FB1_OFF);
        if (has) {
            unsigned bb = FB0_OFF + (unsigned)(nt * 16 + l15) * FSTR + quad * 16;
#pragma unroll
            for (int kk = 0; kk < 6; ++kk) {
                bf16x8 bfr = *(const bf16x8*)(ldsb + bb + kk * 64);
                fa0 = __builtin_amdgcn_mfma_f32_16x16x32_bf16(A2f[kk], bfr, fa0, 0, 0, 0);
                if (dual) fa1 = __builtin_amdgcn_mfma_f32_16x16x32_bf16(A2g[kk], bfr, fa1, 0, 0, 0);
            }
            unsigned short* BmSh = (unsigned short*)(ldsb + BM_OFF);
            int c = nt * 16 + l15;
#pragma unroll
            for (int reg = 0; reg < 4; ++reg) {
                int row = mt0 * 16 + quad * 4 + reg;
                BmSh[row * NCOL + c] = f2bf(fa0[reg]);
                if (dual) BmSh[(row + 16) * NCOL + c] = f2bf(fa1[reg]);
            }
        }
        __syncthreads();
    }

    // ---- main pipeline: chunk i lives in FB1 if i even, FB0 if odd ----
    for (int ch = 0; ch < NCH; ++ch) {
        const int rbuf = (ch & 1) ? FB0_OFF : FB1_OFF;
        const int wbuf = (ch & 1) ? FB1_OFF : FB0_OFF;
        bf16x8 Af[8];
        if (has) {   // hoist row0 A-frags: latency covered by produce below
            const unsigned short* ap =
                Wp + (size_t)(mt0 * 16 + l15) * KDIM + ch * 256 + quad * 8;
#pragma unroll
            for (int kk = 0; kk < 8; ++kk)
                Af[kk] = *(const bf16x8*)(ap + kk * 32);
        }
        if (ch + 1 < NCH) produce((ch + 1) * 64, wbuf);
        if (has) {
            unsigned bb = rbuf + (unsigned)(nt * 16 + l15) * FSTR + quad * 16;
            const unsigned short* ap1 =
                Wp + (size_t)(mt0 * 16 + 16 + l15) * KDIM + ch * 256 + quad * 8;
#pragma unroll
            for (int kk = 0; kk < 8; ++kk) {
                bf16x8 bfr = *(const bf16x8*)(ldsb + bb + kk * 64);
                acc0 = __builtin_amdgcn_mfma_f32_16x16x32_bf16(Af[kk], bfr, acc0, 0, 0, 0);
                if (dual) {
                    bf16x8 a1 = *(const bf16x8*)(ap1 + kk * 32);
                    acc1 = __builtin_amdgcn_mfma_f32_16x16x32_bf16(a1, bfr, acc1, 0, 0, 0);
                }
            }
        }
        __syncthreads();
    }

    // ---- stage partials into aliases over FB0 ----
    float4* pAcc = (float4*)(ldsb + PACC_OFF);
    pAcc[wave * 64 + lane] = make_float4(pbc0, pbc1, pbc2, pbc3);
    if (has) {
        unsigned short* Ash = (unsigned short*)(ldsb + ASH_OFF);
        int c = nt * 16 + l15;
#pragma unroll
        for (int reg = 0; reg < 4; ++reg) {
            int row = mt0 * 16 + quad * 4 + reg;
            Ash[row * NCOL + c] = f2bf(acc0[reg]);
            if (dual) Ash[(row + 16) * NCOL + c] = f2bf(acc1[reg]);
        }
    }
    __syncthreads();

    // ---- epilogue: wave 0, lanes 0..31 = batch cols ----
    if (wave == 0 && lane < 32) {
        float p0 = 0.f, p1 = 0.f, p2 = 0.f, p3 = 0.f;
#pragma unroll
        for (int i = 0; i < 16; ++i) {      // 8 waves x 2 halves
            float4 a = pAcc[i * 32 + col];
            p0 += a.x; p1 += a.y; p2 += a.z; p3 += a.w;
        }
        unsigned short* BmSh = (unsigned short*)(ldsb + BM_OFF);
        unsigned short* Ash  = (unsigned short*)(ldsb + ASH_OFF);
        float t0 = 0.f, t1 = 0.f, t2 = 0.f, t3 = 0.f;
#pragma unroll
        for (int o = 0; o < 10; ++o) {
            float b2r = b2[o * 2 + 0], b2i = b2[o * 2 + 1];
            float b1r = b1[o * 2 + 0], b1i = b1[o * 2 + 1];
            int rb = o * 4;
            float B0r = bf2f(BmSh[(rb + 0) * NCOL + col]) + b2r;
            float B0i = bf2f(BmSh[(rb + 1) * NCOL + col]) + b2i;
            float B1r = bf2f(BmSh[(rb + 2) * NCOL + col]) + b2r;
            float B1i = bf2f(BmSh[(rb + 3) * NCOL + col]) + b2i;
            float A0r = bf2f(Ash[(rb + 0) * NCOL + col]) + b1r;
            float A0i = bf2f(Ash[(rb + 1) * NCOL + col]) + b1i;
            float A1r = bf2f(Ash[(rb + 2) * NCOL + col]) + b1r;
            float A1i = bf2f(Ash[(rb + 3) * NCOL + col]) + b1i;
            float g0 = 2.f * (A0r * B0r + A0i * B0i);
            t0 += g0 * B0r; t1 += g0 * B0i;
            float g1 = 2.f * (A1r * B1r + A1i * B1i);
            t2 += g1 * B1r; t3 += g1 * B1i;
        }
        if (b < B) {
            float dbm = task[(size_t)b * 4 + 0];
            float P   = exp2f(dbm * 0.33219280948873623f) * 0.5f;
            float kP2 = 3.1622776601683794e-05f * P * P;
            float4 Ec = Esh[20 * NCOL + col];    // fp32 center symbol
            float4 o4;
            o4.x = Ec.x + P * p0 + kP2 * t0;
            o4.y = Ec.y + P * p1 + kP2 * t1;
            o4.z = Ec.z + P * p2 + kP2 * t2;
            o4.w = Ec.w + P * p3 + kP2 * t3;
            ((float4*)out)[b] = o4;
        }
    }
}

extern "C" void kernel_launch(void* const* d_in, const int* in_sizes, int n_in,
                              void* d_out, int out_size, void* d_ws, size_t ws_size,
                              hipStream_t stream) {
    const float* x     = (const float*)d_in[0];
    const float* task  = (const float*)d_in[1];
    const float* pbcC  = (const float*)d_in[2];
    const float* W1    = (const float*)d_in[3];
    const float* b1    = (const float*)d_in[4];
    const float* W2    = (const float*)d_in[5];
    const float* b2    = (const float*)d_in[6];
    const int*   m_idx = (const int*)d_in[7];
    const int*   n_idx = (const int*)d_in[8];
    float* out = (float*)d_out;

    int S = in_sizes[7];
    int B = in_sizes[0] / (41 * 2 * 2);

    unsigned short* Wp  = (unsigned short*)d_ws;                      // 286720 B
    unsigned short* W2p = (unsigned short*)((char*)d_ws + 286720);    // 30720 B
    int4*           met = (int4*)((char*)d_ws + 317440);              // S*16 B

    int prep_elems = ROWS * KDIM + ROWS * K2 + S;
    prep_all_kernel<<<(prep_elems + 255) / 256, 256, 0, stream>>>(
        W1, W2, pbcC, m_idx, n_idx, Wp, W2p, met, S);

    int grid = (B + NCOL - 1) / NCOL;
    eqsonn_kernel<<<grid, BLOCK, 0, stream>>>(x, task, Wp, W2p, met, b1, b2,
                                              out, B, S);
}